// Round 4
// baseline (398.699 us; speedup 1.0000x reference)
//
#include <hip/hip_runtime.h>
#include <hip/hip_bf16.h>
#include <stdint.h>
#include <stddef.h>

// ---------------------------------------------------------------------------
// TSPEnergyFunction: out[i,j] = (1 - cos(x1_i, x2_j)) + 0.01 * mi
// mi = mean(t_xy) - (mean(exp(t_sh)) + ln 2) from a MINE critic.
// ALL tensors are float32 (per the reference; rounds 0-3 forensics confirm).
// Internally: convert x and weights to bf16 once, run MFMA GEMMs, apply
// inverse norms + mi in the f32 epilogue. Output stored as f32.
// ---------------------------------------------------------------------------

typedef __attribute__((ext_vector_type(8))) short bf16x8;
typedef __attribute__((ext_vector_type(4))) float f32x4;

__device__ __forceinline__ float bf2f(unsigned short u) {
  union { unsigned int i; float f; } a; a.i = ((unsigned int)u) << 16; return a.f;
}
__device__ __forceinline__ unsigned short f2bf(float f) {
  union { float f; unsigned int i; } a; a.f = f;
  unsigned int r = a.i + 0x7fffu + ((a.i >> 16) & 1u);  // RNE
  return (unsigned short)(r >> 16);
}

#define NROWS 8192
#define DDIM 256
#define CDIM 128
#define HDIM 128

// ---------------------------------------------------------------------------
// 1) Weights prep: f32 -> bf16 transposed weights [n][k]; f32 bias copies;
//    zero the two critic accumulators.
// ---------------------------------------------------------------------------
__global__ __launch_bounds__(256) void k_prep_weights(
    const float* __restrict__ Wc, const float* __restrict__ bc,
    const float* __restrict__ W1, const float* __restrict__ b1,
    const float* __restrict__ W2, const float* __restrict__ b2,
    const float* __restrict__ W3, const float* __restrict__ b3,
    unsigned short* __restrict__ WcT, unsigned short* __restrict__ W1T,
    unsigned short* __restrict__ W2T, float* __restrict__ fsmall,
    float* __restrict__ accum) {
  int t = blockIdx.x * 256 + threadIdx.x;
  int T = gridDim.x * 256;
  for (int i = t; i < DDIM * CDIM; i += T) {
    int k = i >> 7, n = i & 127;          // W[k][n], row-major [256][128]
    WcT[n * DDIM + k] = f2bf(Wc[i]);
    W1T[n * DDIM + k] = f2bf(W1[i]);
  }
  for (int i = t; i < HDIM * HDIM; i += T) {
    int k = i >> 7, n = i & 127;
    W2T[n * HDIM + k] = f2bf(W2[i]);
  }
  if (blockIdx.x == 0) {
    int tt = threadIdx.x;
    if (tt < 128) {
      fsmall[tt]       = bc[tt];
      fsmall[128 + tt] = b1[tt];
      fsmall[256 + tt] = b2[tt];
      fsmall[384 + tt] = W3[tt];
    }
    if (tt == 0) {
      fsmall[512] = b3[0];
      accum[0] = 0.0f; accum[1] = 0.0f;
    }
  }
}

// ---------------------------------------------------------------------------
// 2) Rows prep: f32 x1,x2 -> bf16 xall[16384][256]; f32 inverse row norms
//    (norms computed from the f32 values, matching the reference).
//    One wave per row: 64 lanes x float4.
// ---------------------------------------------------------------------------
__global__ __launch_bounds__(256) void k_prep_rows(
    const float* __restrict__ x1, const float* __restrict__ x2,
    unsigned short* __restrict__ xall,
    float* __restrict__ inva, float* __restrict__ invb) {
  int gtid = blockIdx.x * 256 + threadIdx.x;
  int wv = gtid >> 6;            // 0..16383
  int lane = threadIdx.x & 63;
  int first = (wv < NROWS);
  const float* src = first ? x1 : x2;
  float* invp = first ? inva : invb;
  int row = first ? wv : wv - NROWS;
  float4 v = *((const float4*)(src + (size_t)row * DDIM) + lane);
  ushort4 o;
  o.x = f2bf(v.x); o.y = f2bf(v.y); o.z = f2bf(v.z); o.w = f2bf(v.w);
  *((ushort4*)(xall + (size_t)wv * DDIM) + lane) = o;
  float ss = v.x * v.x + v.y * v.y + v.z * v.z + v.w * v.w;
#pragma unroll
  for (int off = 32; off > 0; off >>= 1) ss += __shfl_xor(ss, off, 64);
  if (lane == 0) invp[row] = 1.0f / fmaxf(sqrtf(ss), 1e-8f);
}

// ---------------------------------------------------------------------------
// 3) Compressor: xc[v] = xall[v] @ Wc + bc (v in [0,16384)), bf16 out.
//    Per wave: 32 rows x 128 cols, MFMA 16x16x32, direct global fragments
//    (WcT stays hot in L2).
// ---------------------------------------------------------------------------
__global__ __launch_bounds__(256) void k_compress(
    const unsigned short* __restrict__ xall,
    const unsigned short* __restrict__ WcT,
    const float* __restrict__ fsmall,
    unsigned short* __restrict__ xc) {
  int lane = threadIdx.x & 63, wave = threadIdx.x >> 6;
  int lm = lane & 15, lq = lane >> 4;
  int r0 = blockIdx.x * 128 + wave * 32;

  f32x4 acc[2][8];
#pragma unroll
  for (int a = 0; a < 2; ++a)
#pragma unroll
    for (int b = 0; b < 8; ++b) acc[a][b] = (f32x4)(0.0f);

  for (int ks = 0; ks < 8; ++ks) {
    int k = ks * 32 + lq * 8;
    bf16x8 a[2], b[8];
#pragma unroll
    for (int tm = 0; tm < 2; ++tm)
      a[tm] = *(const bf16x8*)(xall + (size_t)(r0 + tm * 16 + lm) * DDIM + k);
#pragma unroll
    for (int nt = 0; nt < 8; ++nt)
      b[nt] = *(const bf16x8*)(WcT + (size_t)(nt * 16 + lm) * DDIM + k);
#pragma unroll
    for (int tm = 0; tm < 2; ++tm)
#pragma unroll
      for (int nt = 0; nt < 8; ++nt)
        acc[tm][nt] = __builtin_amdgcn_mfma_f32_16x16x32_bf16(a[tm], b[nt], acc[tm][nt], 0, 0, 0);
  }

#pragma unroll
  for (int tm = 0; tm < 2; ++tm) {
    int row = r0 + tm * 16 + lq * 4;
#pragma unroll
    for (int nt = 0; nt < 8; ++nt) {
      int col = nt * 16 + lm;
      float bcv = fsmall[col];
#pragma unroll
      for (int r = 0; r < 4; ++r)
        xc[(size_t)(row + r) * CDIM + col] = f2bf(acc[tm][nt][r] + bcv);
    }
  }
}

// ---------------------------------------------------------------------------
// 4) Critic: 16384 virtual rows (first 8192 joint, last 8192 shuffled):
//    z = [xc1[i], xc2[i or perm[i]]]; 3-layer MLP; accumulate sum(t)/sum(exp).
// ---------------------------------------------------------------------------
__global__ __launch_bounds__(256) void k_critic(
    const unsigned short* __restrict__ xc, const int* __restrict__ perm,
    const unsigned short* __restrict__ W1T, const unsigned short* __restrict__ W2T,
    const float* __restrict__ fsmall, float* __restrict__ accum) {
  __shared__ __attribute__((aligned(16))) unsigned short h1buf[4][32][136];
  const float* b1 = fsmall + 128;
  const float* b2 = fsmall + 256;
  const float* W3 = fsmall + 384;
  int lane = threadIdx.x & 63, wave = threadIdx.x >> 6;
  int lm = lane & 15, lq = lane >> 4;
  int v0 = blockIdx.x * 128 + wave * 32;
  bool shuffled = (v0 >= NROWS);

  f32x4 acc[2][8];
#pragma unroll
  for (int a = 0; a < 2; ++a)
#pragma unroll
    for (int b = 0; b < 8; ++b) acc[a][b] = (f32x4)(0.0f);

  // layer 1: K = 256 (two 128-halves of z)
  for (int ks = 0; ks < 8; ++ks) {
    int k = ks * 32 + lq * 8;
    bf16x8 a[2], b[8];
#pragma unroll
    for (int tm = 0; tm < 2; ++tm) {
      int i = (v0 + tm * 16 + lm) & (NROWS - 1);
      const unsigned short* zp;
      if (k < CDIM) {
        zp = xc + (size_t)i * CDIM + k;
      } else {
        int j = shuffled ? perm[i] : i;
        zp = xc + (size_t)(NROWS + j) * CDIM + (k - CDIM);
      }
      a[tm] = *(const bf16x8*)zp;
    }
#pragma unroll
    for (int nt = 0; nt < 8; ++nt)
      b[nt] = *(const bf16x8*)(W1T + (size_t)(nt * 16 + lm) * DDIM + k);
#pragma unroll
    for (int tm = 0; tm < 2; ++tm)
#pragma unroll
      for (int nt = 0; nt < 8; ++nt)
        acc[tm][nt] = __builtin_amdgcn_mfma_f32_16x16x32_bf16(a[tm], b[nt], acc[tm][nt], 0, 0, 0);
  }

  // h1 = relu(acc + b1) -> LDS
#pragma unroll
  for (int tm = 0; tm < 2; ++tm)
#pragma unroll
    for (int nt = 0; nt < 8; ++nt) {
      int col = nt * 16 + lm;
      float bv = b1[col];
#pragma unroll
      for (int r = 0; r < 4; ++r) {
        int row = tm * 16 + lq * 4 + r;
        h1buf[wave][row][col] = f2bf(fmaxf(acc[tm][nt][r] + bv, 0.0f));
      }
    }
  __syncthreads();

  // layer 2: K = 128
  f32x4 acc2[2][8];
#pragma unroll
  for (int a = 0; a < 2; ++a)
#pragma unroll
    for (int b = 0; b < 8; ++b) acc2[a][b] = (f32x4)(0.0f);
  for (int ks = 0; ks < 4; ++ks) {
    int k = ks * 32 + lq * 8;
    bf16x8 a[2], b[8];
#pragma unroll
    for (int tm = 0; tm < 2; ++tm)
      a[tm] = *(const bf16x8*)&h1buf[wave][tm * 16 + lm][k];
#pragma unroll
    for (int nt = 0; nt < 8; ++nt)
      b[nt] = *(const bf16x8*)(W2T + (size_t)(nt * 16 + lm) * HDIM + k);
#pragma unroll
    for (int tm = 0; tm < 2; ++tm)
#pragma unroll
      for (int nt = 0; nt < 8; ++nt)
        acc2[tm][nt] = __builtin_amdgcn_mfma_f32_16x16x32_bf16(a[tm], b[nt], acc2[tm][nt], 0, 0, 0);
  }

  // t = relu(acc2 + b2) @ W3 + b3, reduce across the 16-lane group, atomic
  float part[2][4];
#pragma unroll
  for (int tm = 0; tm < 2; ++tm)
#pragma unroll
    for (int r = 0; r < 4; ++r) part[tm][r] = 0.0f;
#pragma unroll
  for (int nt = 0; nt < 8; ++nt) {
    int col = nt * 16 + lm;
    float w3v = W3[col];
    float b2v = b2[col];
#pragma unroll
    for (int tm = 0; tm < 2; ++tm)
#pragma unroll
      for (int r = 0; r < 4; ++r)
        part[tm][r] += fmaxf(acc2[tm][nt][r] + b2v, 0.0f) * w3v;
  }
#pragma unroll
  for (int m = 1; m <= 8; m <<= 1)
#pragma unroll
    for (int tm = 0; tm < 2; ++tm)
#pragma unroll
      for (int r = 0; r < 4; ++r)
        part[tm][r] += __shfl_xor(part[tm][r], m, 64);

  if (lm == 0) {
    float b3v = fsmall[512];
    float local = 0.0f;
#pragma unroll
    for (int tm = 0; tm < 2; ++tm)
#pragma unroll
      for (int r = 0; r < 4; ++r) {
        float tval = part[tm][r] + b3v;
        local += shuffled ? expf(tval) : tval;
      }
    atomicAdd(&accum[shuffled ? 1 : 0], local);
  }
}

// ---------------------------------------------------------------------------
// 5) mi scalar -> additive constant 0.01*mi
// ---------------------------------------------------------------------------
__global__ void k_finalize(const float* __restrict__ accum, float* __restrict__ cadd) {
  float mi = accum[0] / 8192.0f - (accum[1] / 8192.0f + 0.6931471805599453f);
  cadd[0] = 0.01f * mi;
}

// ---------------------------------------------------------------------------
// 6) Main GEMM: out[i][j] = 1 - dot(i,j)*inva[i]*invb[j] + cadd  (f32 out).
//    128x128 tile, BK=64, vector-load staging into padded LDS (stride 72
//    shorts: only 2-way bank aliasing, which is free), 16x16x32 bf16 MFMA,
//    2x2 waves.
// ---------------------------------------------------------------------------
#define LDK 72  // 64 + 8 pad (144 B row stride, 16B-aligned)

__global__ __launch_bounds__(256) void k_dist(
    const unsigned short* __restrict__ A,   // xall rows 0..8191
    const unsigned short* __restrict__ B,   // xall rows 8192..16383
    const float* __restrict__ inva, const float* __restrict__ invb,
    const float* __restrict__ caddp,
    float* __restrict__ out) {
  __shared__ __attribute__((aligned(16))) unsigned short As[128 * LDK];
  __shared__ __attribute__((aligned(16))) unsigned short Bs[128 * LDK];
  int t = threadIdx.x;
  int lane = t & 63, wave = t >> 6;
  int lm = lane & 15, lq = lane >> 4;

  // grouped block swizzle: 8 bm-rows per group for A-tile L2 reuse
  int bid = blockIdx.x;
  int rem = bid & 511;
  int bm = (bid >> 9) * 8 + (rem & 7);
  int bn = rem >> 3;
  int wm = wave >> 1, wn = wave & 1;

  f32x4 acc[4][4];
#pragma unroll
  for (int a = 0; a < 4; ++a)
#pragma unroll
    for (int b = 0; b < 4; ++b) acc[a][b] = (f32x4)(0.0f);

  int srow = t >> 3;              // 0..31
  int sc = (t & 7) * 8;           // 0..56
  const unsigned short* gA = A + (size_t)(bm * 128 + srow) * DDIM + sc;
  const unsigned short* gB = B + (size_t)(bn * 128 + srow) * DDIM + sc;

  for (int kk = 0; kk < 4; ++kk) {
    int k0 = kk * 64;
    bf16x8 va[4], vb[4];
#pragma unroll
    for (int j = 0; j < 4; ++j) {
      va[j] = *(const bf16x8*)(gA + k0 + j * 32 * DDIM);
      vb[j] = *(const bf16x8*)(gB + k0 + j * 32 * DDIM);
    }
    __syncthreads();  // prior LDS reads must complete before overwrite
#pragma unroll
    for (int j = 0; j < 4; ++j) {
      *(bf16x8*)(As + (srow + j * 32) * LDK + sc) = va[j];
      *(bf16x8*)(Bs + (srow + j * 32) * LDK + sc) = vb[j];
    }
    __syncthreads();
#pragma unroll
    for (int ko = 0; ko < 64; ko += 32) {
      bf16x8 a[4], b[4];
      int cp = ko + lq * 8;
#pragma unroll
      for (int tm = 0; tm < 4; ++tm)
        a[tm] = *(const bf16x8*)(As + (wm * 64 + tm * 16 + lm) * LDK + cp);
#pragma unroll
      for (int tn = 0; tn < 4; ++tn)
        b[tn] = *(const bf16x8*)(Bs + (wn * 64 + tn * 16 + lm) * LDK + cp);
#pragma unroll
      for (int tm = 0; tm < 4; ++tm)
#pragma unroll
        for (int tn = 0; tn < 4; ++tn)
          acc[tm][tn] = __builtin_amdgcn_mfma_f32_16x16x32_bf16(a[tm], b[tn], acc[tm][tn], 0, 0, 0);
    }
  }

  float cadd = *caddp;
#pragma unroll
  for (int tm = 0; tm < 4; ++tm) {
    int gr0 = bm * 128 + wm * 64 + tm * 16 + lq * 4;
#pragma unroll
    for (int tn = 0; tn < 4; ++tn) {
      int gc = bn * 128 + wn * 64 + tn * 16 + lm;
      float ib = invb[gc];
#pragma unroll
      for (int r = 0; r < 4; ++r)
        out[(size_t)(gr0 + r) * 8192 + gc] =
            1.0f - acc[tm][tn][r] * inva[gr0 + r] * ib + cadd;
    }
  }
}

// ---------------------------------------------------------------------------
extern "C" void kernel_launch(void* const* d_in, const int* in_sizes, int n_in,
                              void* d_out, int out_size, void* d_ws, size_t ws_size,
                              hipStream_t stream) {
  const float* x1 = (const float*)d_in[0];
  const float* x2 = (const float*)d_in[1];
  const float* Wc = (const float*)d_in[2];
  const float* bc = (const float*)d_in[3];
  const float* W1 = (const float*)d_in[4];
  const float* b1 = (const float*)d_in[5];
  const float* W2 = (const float*)d_in[6];
  const float* b2 = (const float*)d_in[7];
  const float* W3 = (const float*)d_in[8];
  const float* b3 = (const float*)d_in[9];
  const int* perm = (const int*)d_in[10];
  float* out = (float*)d_out;

  char* ws = (char*)d_ws;
  unsigned short* xall = (unsigned short*)ws;                          // 8 MB
  unsigned short* xc   = (unsigned short*)(ws + (8u << 20));           // 4 MB
  unsigned short* WcT  = (unsigned short*)(ws + (12u << 20));          // 64 KB
  unsigned short* W1T  = (unsigned short*)(ws + (12u << 20) + 65536);  // 64 KB
  unsigned short* W2T  = (unsigned short*)(ws + (12u << 20) + 131072); // 32 KB
  float* fsmall = (float*)(ws + (12u << 20) + 163840);                 // 2052 B
  float* inva  = (float*)(ws + (12u << 20) + 167936);                  // 32 KB
  float* invb  = (float*)(ws + (12u << 20) + 200704);                  // 32 KB
  float* accum = (float*)(ws + (12u << 20) + 233472);                  // 8 B
  float* cadd  = (float*)(ws + (12u << 20) + 233480);                  // 4 B

  k_prep_weights<<<32, 256, 0, stream>>>(Wc, bc, W1, b1, W2, b2, W3, b3,
                                         WcT, W1T, W2T, fsmall, accum);
  k_prep_rows<<<4096, 256, 0, stream>>>(x1, x2, xall, inva, invb);
  k_compress<<<128, 256, 0, stream>>>(xall, WcT, fsmall, xc);
  k_critic<<<128, 256, 0, stream>>>(xc, perm, W1T, W2T, fsmall, accum);
  k_finalize<<<1, 1, 0, stream>>>(accum, cadd);
  k_dist<<<4096, 256, 0, stream>>>(xall, xall + (size_t)NROWS * DDIM,
                                   inva, invb, cadd, out);
}